// Round 1
// baseline (52.043 us; speedup 1.0000x reference)
//
#include <hip/hip_runtime.h>
#include <float.h>

// Problem constants (match reference)
#define BB 2
#define CC 128
#define NN 4096
#define MM 16384
#define NCHUNK 4
#define CHUNK (NN / NCHUNK)   // 1024 points per chunk -> 16KB LDS
#define AB 256                // anchors per block in the knn kernel

// ---------------------------------------------------------------------------
// Kernel A: partial 1-NN argmin over one chunk of source points.
// grid.x = (BB*MM/AB) * NCHUNK = 512 blocks, block = 256 threads.
// Each thread owns one anchor; block stages CHUNK points (x0,x1,x2,||x||^2)
// in LDS; inner loop is 3 FMA per point (score = ||x||^2 - 2 a.x, same argmin
// as full squared distance since ||a||^2 is constant per anchor).
// First-index tie-break everywhere (matches jnp.argmin).
// ---------------------------------------------------------------------------
__global__ __launch_bounds__(256) void knn_chunk_kernel(
    const float* __restrict__ xyz,      // [B,3,N]
    const float* __restrict__ anchor,   // [B,3,M]
    float* __restrict__ wd,             // [NCHUNK, B*M] partial best score
    int*   __restrict__ wi)             // [NCHUNK, B*M] partial best index
{
    __shared__ float4 pts[CHUNK];
    const int blk   = blockIdx.x;
    const int chunk = blk % NCHUNK;
    const int g     = blk / NCHUNK;          // anchor group 0..(B*M/AB - 1)
    const int b     = g / (MM / AB);
    const int m0    = (g % (MM / AB)) * AB;
    const int t     = threadIdx.x;

    // stage chunk points into LDS (coalesced)
    const float* xb = xyz + b * 3 * NN;
    const int nbase = chunk * CHUNK;
    #pragma unroll
    for (int k = 0; k < CHUNK / 256; ++k) {
        int nl = k * 256 + t;
        float x0 = xb[nbase + nl];
        float x1 = xb[NN + nbase + nl];
        float x2 = xb[2 * NN + nbase + nl];
        float xx = fmaf(x0, x0, fmaf(x1, x1, x2 * x2));
        pts[nl] = make_float4(x0, x1, x2, xx);
    }
    __syncthreads();

    const int m = m0 + t;
    const float* ab_ = anchor + b * 3 * MM;
    float a0 = ab_[m], a1 = ab_[MM + m], a2 = ab_[2 * MM + m];
    float na0 = -2.0f * a0, na1 = -2.0f * a1, na2 = -2.0f * a2;

    float dmin = FLT_MAX;
    int   imin = nbase;

    for (int n = 0; n < CHUNK; n += 8) {
        float d[8];
        #pragma unroll
        for (int k = 0; k < 8; ++k) {
            float4 p = pts[n + k];           // wave-uniform address -> broadcast
            float v = fmaf(na0, p.x, p.w);
            v = fmaf(na1, p.y, v);
            d[k] = fmaf(na2, p.z, v);
        }
        // tree argmin, lower index wins ties (<=)
        int   i01 = (d[0] <= d[1]) ? 0 : 1;  float d01 = fminf(d[0], d[1]);
        int   i23 = (d[2] <= d[3]) ? 2 : 3;  float d23 = fminf(d[2], d[3]);
        int   i45 = (d[4] <= d[5]) ? 4 : 5;  float d45 = fminf(d[4], d[5]);
        int   i67 = (d[6] <= d[7]) ? 6 : 7;  float d67 = fminf(d[6], d[7]);
        int   i03 = (d01 <= d23) ? i01 : i23; float d03 = fminf(d01, d23);
        int   i47 = (d45 <= d67) ? i45 : i67; float d47 = fminf(d45, d67);
        int   i07 = (d03 <= d47) ? i03 : i47; float d07 = fminf(d03, d47);
        if (d07 < dmin) { dmin = d07; imin = nbase + n + i07; }  // strict <: keep first
    }

    const int bm = b * MM + m;
    wd[chunk * (BB * MM) + bm] = dmin;
    wi[chunk * (BB * MM) + bm] = imin;
}

// ---------------------------------------------------------------------------
// Kernel B: combine NCHUNK partial candidates per anchor (strict < keeps the
// lowest-index chunk on ties), then bitwise exact-match test of NN coords vs
// anchor coords. sel = exact ? idx : -1.
// ---------------------------------------------------------------------------
__global__ __launch_bounds__(256) void combine_kernel(
    const float* __restrict__ xyz,      // [B,3,N]
    const float* __restrict__ anchor,   // [B,3,M]
    const float* __restrict__ wd,
    const int*   __restrict__ wi,
    int* __restrict__ sel)              // [B*M]
{
    const int bm = blockIdx.x * 256 + threadIdx.x;   // < B*M
    const int b = bm / MM;
    const int m = bm % MM;

    float dbest = wd[bm];
    int   ibest = wi[bm];
    #pragma unroll
    for (int ch = 1; ch < NCHUNK; ++ch) {
        float dv = wd[ch * (BB * MM) + bm];
        int   iv = wi[ch * (BB * MM) + bm];
        if (dv < dbest) { dbest = dv; ibest = iv; }  // strict <: earlier chunk wins ties
    }

    const float* xb  = xyz + b * 3 * NN;
    const float* ab_ = anchor + b * 3 * MM;
    bool exact = (xb[ibest]          == ab_[m]) &&
                 (xb[NN + ibest]     == ab_[MM + m]) &&
                 (xb[2 * NN + ibest] == ab_[2 * MM + m]);
    sel[bm] = exact ? ibest : -1;
}

// ---------------------------------------------------------------------------
// Kernel C: gather features. One thread per element of out1 [B,C,M].
// ---------------------------------------------------------------------------
__global__ __launch_bounds__(256) void gather_kernel(
    const float* __restrict__ feature,  // [B,C,N]
    const int*   __restrict__ sel,      // [B*M]
    float* __restrict__ out1)           // [B,C,M]
{
    const int o = blockIdx.x * 256 + threadIdx.x;    // < B*C*M
    const int m = o & (MM - 1);
    const int c = (o >> 14) & (CC - 1);              // M = 2^14
    const int b = o >> 21;                           // C*M = 2^21
    const int s = sel[b * MM + m];
    float v = 0.0f;
    if (s >= 0) v = feature[(b * CC + c) * NN + s];
    out1[o] = v;
}

extern "C" void kernel_launch(void* const* d_in, const int* in_sizes, int n_in,
                              void* d_out, int out_size, void* d_ws, size_t ws_size,
                              hipStream_t stream) {
    const float* xyz    = (const float*)d_in[0];  // [B,3,N]
    const float* feat   = (const float*)d_in[1];  // [B,C,N]
    const float* anchor = (const float*)d_in[2];  // [B,3,M]

    float* out0 = (float*)d_out;                  // [B,3,M] passthrough
    float* out1 = out0 + BB * 3 * MM;             // [B,C,M]

    // workspace layout: wd (4*B*M floats) | wi (4*B*M ints) | sel (B*M ints)
    float* wd  = (float*)d_ws;
    int*   wi  = (int*)(wd + NCHUNK * BB * MM);
    int*   sel = wi + NCHUNK * BB * MM;

    // output 0: exact passthrough of xyz_anchor
    hipMemcpyAsync(out0, anchor, (size_t)BB * 3 * MM * sizeof(float),
                   hipMemcpyDeviceToDevice, stream);

    knn_chunk_kernel<<<(BB * MM / AB) * NCHUNK, 256, 0, stream>>>(xyz, anchor, wd, wi);
    combine_kernel<<<BB * MM / 256, 256, 0, stream>>>(xyz, anchor, wd, wi, sel);
    gather_kernel<<<BB * CC * MM / 256, 256, 0, stream>>>(feat, sel, out1);
}